// Round 1
// baseline (690.188 us; speedup 1.0000x reference)
//
#include <hip/hip_runtime.h>
#include <stdint.h>

typedef unsigned long long ull;

#define NPGC 512
#define EPGC 4096
#define DC 8
#define GATEC 64
#define NEGF (-1e30f)
#define NTHREADS 256
#define ETOT 4194304

union SortRed {
    ull key[NPGC];                                  // 4096 B (top-k sort)
    struct { float r1[4][GATEC]; float r2[4][GATEC]; } red;  // 2048 B (att reduce)
};

__global__ __launch_bounds__(NTHREADS, 4)
void gce_kernel(const float* __restrict__ x,
                const float* __restrict__ Wc,
                const float* __restrict__ bc,
                const float* __restrict__ pvec,
                const float* __restrict__ Wg,
                const float* __restrict__ bg,
                const int* __restrict__ ei,
                float* __restrict__ out)
{
    __shared__ float X[DC][NPGC];   // 16 KB  current features (column-major)
    __shared__ float Y[DC][NPGC];   // 16 KB  h @ W
    __shared__ float maskf[NPGC];   //  2 KB
    __shared__ float degv[NPGC];    //  2 KB  deg -> dinv -> keep-codes -> chan max
    __shared__ SortRed u;           //  4 KB
    // total 40960 B -> 4 blocks/CU, all 1024 blocks resident

    const int tid = threadIdx.x;
    const int g   = blockIdx.x;
    const int c   = tid & 63;       // attention channel
    const int grp = tid >> 6;       // attention node-group (wave id)

    // per-thread Wg column + bias (lives in regs for the whole kernel)
    float wgc[8];
#pragma unroll
    for (int j = 0; j < 8; ++j) wgc[j] = Wg[j * 64 + c];
    const float bgc = bg[c];

    // ---- load x for this graph into X (transpose to column-major), mask=1
    for (int n = tid; n < NPGC; n += NTHREADS) {
        const float* xr = x + ((size_t)g * NPGC + n) * DC;
        float4 a = *reinterpret_cast<const float4*>(xr);
        float4 b = *reinterpret_cast<const float4*>(xr + 4);
        X[0][n] = a.x; X[1][n] = a.y; X[2][n] = a.z; X[3][n] = a.w;
        X[4][n] = b.x; X[5][n] = b.y; X[6][n] = b.z; X[7][n] = b.w;
        maskf[n] = 1.0f;
    }

    const int* rowp = ei;
    const int* colp = ei + ETOT;
    const size_t eb = (size_t)g * EPGC + (size_t)tid * 16;  // 16 edges/thread

    float out_acc = 0.0f;

#pragma unroll 1
    for (int layer = 0; layer < 4; ++layer) {
        const float* Wl = Wc + layer * 64;
        const float* bl = bc + layer * 8;
        const float* pl = pvec + layer * 8;
        const int kk = (layer == 0) ? 410 : (layer == 1) ? 328 : (layer == 2) ? 263 : 211;

        __syncthreads();  // protects X/maskf from previous phase
        // ---- deg init (self-loop term: +mask_f)
        for (int n = tid; n < NPGC; n += NTHREADS) degv[n] = maskf[n];
        __syncthreads();

        // ---- phase 1: Y = X @ W  (per-node 8x8 matvec)  +  deg atomics
        for (int n = tid; n < NPGC; n += NTHREADS) {
            float hv[8];
#pragma unroll
            for (int j = 0; j < 8; ++j) hv[j] = X[j][n];
#pragma unroll
            for (int k = 0; k < 8; ++k) {
                float acc = 0.f;
#pragma unroll
                for (int j = 0; j < 8; ++j) acc += hv[j] * Wl[j * 8 + k];
                Y[k][n] = acc;
            }
        }
#pragma unroll
        for (int i = 0; i < 4; ++i) {
            int4 r4 = *reinterpret_cast<const int4*>(rowp + eb + i * 4);
            int4 c4 = *reinterpret_cast<const int4*>(colp + eb + i * 4);
            int rl[4] = {r4.x & 511, r4.y & 511, r4.z & 511, r4.w & 511};
            int cl[4] = {c4.x & 511, c4.y & 511, c4.z & 511, c4.w & 511};
#pragma unroll
            for (int q = 0; q < 4; ++q) {
                if (maskf[rl[q]] * maskf[cl[q]] > 0.f)
                    atomicAdd(&degv[cl[q]], 1.0f);
            }
        }
        __syncthreads();

        // ---- phase 2: dinv = deg^-0.5 ; X = self-loop term
        for (int n = tid; n < NPGC; n += NTHREADS) {
            float dg = degv[n];
            float di = (dg > 0.f) ? (1.0f / sqrtf(dg)) : 0.f;
            degv[n] = di;
            float c0 = di * di * maskf[n];
#pragma unroll
            for (int k = 0; k < 8; ++k) X[k][n] = Y[k][n] * c0;
        }
        __syncthreads();

        // ---- phase 3: edge scatter  X[:,col] += Y[:,row] * dinv[row]*dinv[col]
#pragma unroll
        for (int i = 0; i < 4; ++i) {
            int4 r4 = *reinterpret_cast<const int4*>(rowp + eb + i * 4);
            int4 c4 = *reinterpret_cast<const int4*>(colp + eb + i * 4);
            int rls[4] = {r4.x & 511, r4.y & 511, r4.z & 511, r4.w & 511};
            int cls[4] = {c4.x & 511, c4.y & 511, c4.z & 511, c4.w & 511};
#pragma unroll
            for (int q = 0; q < 4; ++q) {
                int rl = rls[q], cl = cls[q];
                if (maskf[rl] * maskf[cl] > 0.f) {
                    float nrm = degv[rl] * degv[cl];
#pragma unroll
                    for (int k = 0; k < 8; ++k)
                        atomicAdd(&X[k][cl], Y[k][rl] * nrm);
                }
            }
        }
        __syncthreads();

        // ---- phase 4: (+bias)*mask, relu, score, build sort key
        {
            float pv[8];
            float ss = 0.f;
#pragma unroll
            for (int k = 0; k < 8; ++k) { pv[k] = pl[k]; ss += pv[k] * pv[k]; }
            const float pn = sqrtf(ss);
            for (int n = tid; n < NPGC; n += NTHREADS) {
                float mf = maskf[n];
                float dot = 0.f;
#pragma unroll
                for (int k = 0; k < 8; ++k) {
                    float v = (X[k][n] + bl[k]) * mf;
                    v = fmaxf(v, 0.f);
                    X[k][n] = v;
                    dot += v * pv[k];
                }
                float s  = tanhf(dot / pn);
                float sm = (mf > 0.f) ? s : NEGF;
                // ascending-sortable u32 of float (XLA total order incl. -0 < +0)
                unsigned ub  = __float_as_uint(sm);
                unsigned asc = (ub & 0x80000000u) ? ~ub : (ub | 0x80000000u);
                unsigned dsc = ~asc;  // descending score, ties -> index ascending
                u.key[n] = ((ull)dsc << 32) | (unsigned)n;
            }
        }
        __syncthreads();

        // ---- phase 5: bitonic sort of 512 u64 keys, ascending
        for (int size = 2; size <= NPGC; size <<= 1) {
            for (int stride = size >> 1; stride > 0; stride >>= 1) {
                int i = ((tid & ~(stride - 1)) << 1) | (tid & (stride - 1));
                int j = i | stride;
                bool asc = (i & size) == 0;
                ull a = u.key[i], b = u.key[j];
                bool sw = asc ? (a > b) : (a < b);
                if (sw) { u.key[i] = b; u.key[j] = a; }
                __syncthreads();
            }
        }

        // ---- phase 6: top-k keep set, update mask, scale X by score
        {
            unsigned* keepu = reinterpret_cast<unsigned*>(degv);
            for (int n = tid; n < NPGC; n += NTHREADS) keepu[n] = 0xFFFFFFFFu;
            __syncthreads();
            for (int pos = tid; pos < kk; pos += NTHREADS) {
                ull kv = u.key[pos];
                unsigned node = (unsigned)(kv & 0xFFFFFFFFull);
                unsigned a  = ~((unsigned)(kv >> 32));               // asc code
                unsigned fb = (a & 0x80000000u) ? (a ^ 0x80000000u) : ~a; // f32 bits
                keepu[node] = fb;
            }
            __syncthreads();
            for (int n = tid; n < NPGC; n += NTHREADS) {
                unsigned uv = keepu[n];
                if (uv != 0xFFFFFFFFu) {
                    float sv = __uint_as_float(uv);
                    maskf[n] = 1.0f;
#pragma unroll
                    for (int k = 0; k < 8; ++k) X[k][n] *= sv;
                } else {
                    maskf[n] = 0.0f;
#pragma unroll
                    for (int k = 0; k < 8; ++k) X[k][n] = 0.f;
                }
            }
        }
        __syncthreads();

        // ---- phase 7: attention pool, pass 1 (per-channel max over valid nodes)
        {
            float mloc = NEGF;
            for (int i = 0; i < NPGC / 4; ++i) {
                int n = grp * (NPGC / 4) + i;     // wave-uniform node
                if (maskf[n] > 0.f) {             // wave-uniform branch
                    float gv = bgc;
#pragma unroll
                    for (int j = 0; j < 8; ++j) gv += X[j][n] * wgc[j];  // LDS broadcast
                    mloc = fmaxf(mloc, gv);
                }
            }
            u.red.r1[grp][c] = mloc;
            __syncthreads();
            if (tid < 64) {
                float m = fmaxf(fmaxf(u.red.r1[0][tid], u.red.r1[1][tid]),
                                fmaxf(u.red.r1[2][tid], u.red.r1[3][tid]));
                degv[tid] = m;   // stash channel max (degv dead here)
            }
            __syncthreads();
            const float mc = degv[c];

            // pass 2: exp-sum and weighted sum
            float esum = 0.f, wsum = 0.f;
            for (int i = 0; i < NPGC / 4; ++i) {
                int n = grp * (NPGC / 4) + i;
                if (maskf[n] > 0.f) {
                    float gv = bgc;
#pragma unroll
                    for (int j = 0; j < 8; ++j) gv += X[j][n] * wgc[j];
                    float e = expf(gv - mc);
                    esum += e;
                    wsum += e * gv;
                }
            }
            u.red.r1[grp][c] = esum;
            u.red.r2[grp][c] = wsum;
            __syncthreads();
            if (tid < 64) {
                float es = u.red.r1[0][tid] + u.red.r1[1][tid] + u.red.r1[2][tid] + u.red.r1[3][tid];
                float ws = u.red.r2[0][tid] + u.red.r2[1][tid] + u.red.r2[2][tid] + u.red.r2[3][tid];
                out_acc += ws / es;
            }
        }
    }

    if (tid < 64) out[(size_t)g * 64 + tid] = out_acc;
}

extern "C" void kernel_launch(void* const* d_in, const int* in_sizes, int n_in,
                              void* d_out, int out_size, void* d_ws, size_t ws_size,
                              hipStream_t stream) {
    const float* x    = (const float*)d_in[0];
    const float* Wc   = (const float*)d_in[1];
    const float* bc   = (const float*)d_in[2];
    const float* pvec = (const float*)d_in[3];
    const float* Wg   = (const float*)d_in[4];
    const float* bg   = (const float*)d_in[5];
    const int*   ei   = (const int*)d_in[6];
    float* out = (float*)d_out;

    gce_kernel<<<dim3(1024), dim3(NTHREADS), 0, stream>>>(x, Wc, bc, pvec, Wg, bg, ei, out);
}

// Round 2
// 670.507 us; speedup vs baseline: 1.0294x; 1.0294x over previous
//
#include <hip/hip_runtime.h>
#include <stdint.h>

typedef unsigned long long ull;

#define NPGC 512
#define EPGC 4096
#define NTHREADS 256
#define ETOT 4194304
#define NEGF (-1e30f)

union SortRed {
    ull key[NPGC];                                   // 4096 B: score keys
    struct { float r1[4][64]; float r2[4][64]; } red; // 2048 B: attention reduce
};

__global__ __launch_bounds__(NTHREADS, 4)
void gce_kernel(const float* __restrict__ x,
                const float* __restrict__ Wc,
                const float* __restrict__ bc,
                const float* __restrict__ pvec,
                const float* __restrict__ Wg,
                const float* __restrict__ bg,
                const int* __restrict__ ei,
                float* __restrict__ out)
{
    __shared__ float X[8][NPGC];    // 16 KB current features (channel-major)
    __shared__ float Y[8][NPGC];    // 16 KB h @ W
    __shared__ float maskf[NPGC];   //  2 KB
    __shared__ float degv[NPGC];    //  2 KB deg/dinv; later comp16[512] + chanmax[64]
    __shared__ SortRed u;           //  4 KB
    // total exactly 40960 B -> 4 blocks/CU, all 1024 blocks resident

    const int tid = threadIdx.x;
    const int g   = blockIdx.x;
    const int c   = tid & 63;       // attention channel
    const int grp = tid >> 6;       // wave id
    const int n0  = tid, n1 = tid + 256;

    unsigned short* comp16 = reinterpret_cast<unsigned short*>(degv); // bytes [0,1024)
    float* chmax = degv + 256;                                        // bytes [1024,1280)

    // per-thread Wg column + bias (registers for whole kernel)
    float wgc[8];
#pragma unroll
    for (int j = 0; j < 8; ++j) wgc[j] = Wg[j * 64 + c];
    const float bgc = bg[c];

    // ---- preload this thread's 16 edges, packed (row | col<<16), local ids
    uint32_t er[16];
    {
        const int* rowp = ei;
        const int* colp = ei + ETOT;
        const size_t eb = (size_t)g * EPGC + (size_t)tid * 16;
#pragma unroll
        for (int i = 0; i < 4; ++i) {
            int4 r4 = *reinterpret_cast<const int4*>(rowp + eb + i * 4);
            int4 c4 = *reinterpret_cast<const int4*>(colp + eb + i * 4);
            er[i * 4 + 0] = (uint32_t)(r4.x & 511) | ((uint32_t)(c4.x & 511) << 16);
            er[i * 4 + 1] = (uint32_t)(r4.y & 511) | ((uint32_t)(c4.y & 511) << 16);
            er[i * 4 + 2] = (uint32_t)(r4.z & 511) | ((uint32_t)(c4.z & 511) << 16);
            er[i * 4 + 3] = (uint32_t)(r4.w & 511) | ((uint32_t)(c4.w & 511) << 16);
        }
    }

    // ---- load x into X (transpose to channel-major), mask = 1
    for (int n = tid; n < NPGC; n += NTHREADS) {
        const float* xr = x + ((size_t)g * NPGC + n) * 8;
        float4 a = *reinterpret_cast<const float4*>(xr);
        float4 b = *reinterpret_cast<const float4*>(xr + 4);
        X[0][n] = a.x; X[1][n] = a.y; X[2][n] = a.z; X[3][n] = a.w;
        X[4][n] = b.x; X[5][n] = b.y; X[6][n] = b.z; X[7][n] = b.w;
        maskf[n] = 1.0f;
    }

    float out_acc = 0.0f;

#pragma unroll 1
    for (int layer = 0; layer < 4; ++layer) {
        const float* Wl = Wc + layer * 64;
        const float* bl = bc + layer * 8;
        const float* pl = pvec + layer * 8;
        const int kk = (layer == 0) ? 410 : (layer == 1) ? 328 : (layer == 2) ? 263 : 211;

        __syncthreads();                  // X/maskf ready; degv (comp/chmax) dead
        degv[n0] = maskf[n0];
        degv[n1] = maskf[n1];
        __syncthreads();

        // ---- phase 1: Y = X @ W (valid nodes) + degree atomics
#pragma unroll
        for (int t = 0; t < 2; ++t) {
            const int n = t ? n1 : n0;
            if (maskf[n] > 0.f) {
                float hv[8];
#pragma unroll
                for (int j = 0; j < 8; ++j) hv[j] = X[j][n];
#pragma unroll
                for (int k = 0; k < 8; ++k) {
                    float acc = 0.f;
#pragma unroll
                    for (int j = 0; j < 8; ++j) acc += hv[j] * Wl[j * 8 + k];
                    Y[k][n] = acc;
                }
            }
        }
#pragma unroll
        for (int i = 0; i < 16; ++i) {
            const int rl = er[i] & 0xffff, cl = er[i] >> 16;
            if (maskf[rl] > 0.f && maskf[cl] > 0.f)
                atomicAdd(&degv[cl], 1.0f);
        }
        __syncthreads();

        // ---- phase 2: dinv = deg^-0.5 (0 for invalid) ; X = self-loop term
#pragma unroll
        for (int t = 0; t < 2; ++t) {
            const int n = t ? n1 : n0;
            const float dg = degv[n];
            const float di = (dg > 0.f) ? rsqrtf(dg) : 0.f;
            degv[n] = di;                 // own slot: no race
            if (maskf[n] > 0.f) {
                const float c0 = di * di;
#pragma unroll
                for (int k = 0; k < 8; ++k) X[k][n] = Y[k][n] * c0;
            }
        }
        __syncthreads();

        // ---- phase 3: edge scatter  X[:,col] += Y[:,row] * dinv[row]*dinv[col]
#pragma unroll
        for (int i = 0; i < 16; ++i) {
            const int rl = er[i] & 0xffff, cl = er[i] >> 16;
            const float nrm = degv[rl] * degv[cl];   // 0 unless both valid
            if (nrm > 0.f) {
#pragma unroll
                for (int k = 0; k < 8; ++k)
                    atomicAdd(&X[k][cl], Y[k][rl] * nrm);
            }
        }
        __syncthreads();

        // ---- phase 4: (+bias)*mask, relu, score, sort key (key kept in regs)
        float s0, s1;
        ull key0, key1;
        {
            float pv[8], ss = 0.f;
#pragma unroll
            for (int k = 0; k < 8; ++k) { pv[k] = pl[k]; ss += pv[k] * pv[k]; }
            const float pn = sqrtf(ss);
#pragma unroll
            for (int t = 0; t < 2; ++t) {
                const int n = t ? n1 : n0;
                const float mf = maskf[n];
                float dot = 0.f;
#pragma unroll
                for (int k = 0; k < 8; ++k) {
                    float v = (X[k][n] + bl[k]) * mf;
                    v = fmaxf(v, 0.f);
                    X[k][n] = v;
                    dot += v * pv[k];
                }
                const float s  = tanhf(dot / pn);
                const float sm = (mf > 0.f) ? s : NEGF;
                const unsigned ub  = __float_as_uint(sm);
                const unsigned asc = (ub & 0x80000000u) ? ~ub : (ub | 0x80000000u);
                const ull key = ((ull)(~asc) << 32) | (unsigned)n;
                u.key[n] = key;
                if (t) { s1 = s; key1 = key; } else { s0 = s; key0 = key; }
            }
        }
        __syncthreads();

        // ---- phase 5: rank by counting (broadcast reads, branch-free)
        int r0 = 0, r1 = 0;
#pragma unroll 8
        for (int j = 0; j < NPGC; j += 2) {
            const ull ka = u.key[j];
            const ull kb = u.key[j + 1];
            r0 += (int)(ka < key0) + (int)(kb < key0);
            r1 += (int)(ka < key1) + (int)(kb < key1);
        }
        // masked nodes: key is maximal -> rank >= n_valid >= kk, never kept.

        // ---- phase 6: keep top-k, scale X, build compacted list (own slots only)
#pragma unroll
        for (int t = 0; t < 2; ++t) {
            const int n = t ? n1 : n0;
            const int r = t ? r1 : r0;
            const float s = t ? s1 : s0;
            if (r < kk) {
                comp16[r] = (unsigned short)n;
#pragma unroll
                for (int k = 0; k < 8; ++k) X[k][n] *= s;
            } else {
                maskf[n] = 0.f;
#pragma unroll
                for (int k = 0; k < 8; ++k) X[k][n] = 0.f;
            }
        }
        __syncthreads();

        // ---- phase 7: attention pool over compacted valid list
        {
            float mloc = NEGF;
            for (int i = grp; i < kk; i += 4) {          // wave-uniform node
                const int n = comp16[i];
                float gv = bgc;
#pragma unroll
                for (int j = 0; j < 8; ++j) gv += X[j][n] * wgc[j];  // LDS broadcast
                mloc = fmaxf(mloc, gv);
            }
            u.red.r1[grp][c] = mloc;
            __syncthreads();
            if (tid < 64) {
                chmax[tid] = fmaxf(fmaxf(u.red.r1[0][tid], u.red.r1[1][tid]),
                                   fmaxf(u.red.r1[2][tid], u.red.r1[3][tid]));
            }
            __syncthreads();
            const float mc = chmax[c];

            float esum = 0.f, wsum = 0.f;
            for (int i = grp; i < kk; i += 4) {
                const int n = comp16[i];
                float gv = bgc;
#pragma unroll
                for (int j = 0; j < 8; ++j) gv += X[j][n] * wgc[j];
                const float e = __expf(gv - mc);
                esum += e;
                wsum += e * gv;
            }
            u.red.r1[grp][c] = esum;
            u.red.r2[grp][c] = wsum;
            __syncthreads();
            if (tid < 64) {
                const float es = u.red.r1[0][tid] + u.red.r1[1][tid] +
                                 u.red.r1[2][tid] + u.red.r1[3][tid];
                const float ws = u.red.r2[0][tid] + u.red.r2[1][tid] +
                                 u.red.r2[2][tid] + u.red.r2[3][tid];
                out_acc += ws / es;
            }
        }
    }

    if (tid < 64) out[(size_t)g * 64 + tid] = out_acc;
}

extern "C" void kernel_launch(void* const* d_in, const int* in_sizes, int n_in,
                              void* d_out, int out_size, void* d_ws, size_t ws_size,
                              hipStream_t stream) {
    const float* x    = (const float*)d_in[0];
    const float* Wc   = (const float*)d_in[1];
    const float* bc   = (const float*)d_in[2];
    const float* pvec = (const float*)d_in[3];
    const float* Wg   = (const float*)d_in[4];
    const float* bg   = (const float*)d_in[5];
    const int*   ei   = (const int*)d_in[6];
    float* out = (float*)d_out;

    gce_kernel<<<dim3(1024), dim3(NTHREADS), 0, stream>>>(x, Wc, bc, pvec, Wg, bg, ei, out);
}